// Round 5
// baseline (823.293 us; speedup 1.0000x reference)
//
#include <hip/hip_runtime.h>

typedef __bf16 bf16x8 __attribute__((ext_vector_type(8)));
typedef float floatx4 __attribute__((ext_vector_type(4)));

#define MFMA16(a, b, c) __builtin_amdgcn_mfma_f32_16x16x32_bf16((a), (b), (c), 0, 0, 0)

constexpr int D_MODEL = 1024;
constexpr int SEQ = 2048;
constexpr int HEAD_DIM = 64;
constexpr int M_TOK = 2 * SEQ;   // 4096 tokens (B=2)
constexpr int N_HEADS = 16;
constexpr float ROPE_C = 0.20762050593048596f;   // log2(10000)/64

// 8-element bf16 fragment from fp32 memory (2x float4 + convert)
__device__ __forceinline__ bf16x8 load8f(const float* f)
{
    const floatx4 lo = *(const floatx4*)f;
    const floatx4 hi = *(const floatx4*)(f + 4);
    bf16x8 v;
    v[0] = (__bf16)lo[0]; v[1] = (__bf16)lo[1]; v[2] = (__bf16)lo[2]; v[3] = (__bf16)lo[3];
    v[4] = (__bf16)hi[0]; v[5] = (__bf16)hi[1]; v[6] = (__bf16)hi[2]; v[7] = (__bf16)hi[3];
    return v;
}

// ---------------------------------------------------------------------------
// C[M][1024] = A[M][1024] . W[1024][1024]^T.  A is fp32 (aBf=0) or bf16
// (aBf=1); W is fp32.  Output: float (Cf) or bf16 (Cb) — exactly one non-null.
// One wave per block; 16(M) x 64(N) strip, 4 MFMA accumulators.  Optional
// fused RoPE (pairs = adjacent cols = adjacent lanes -> shfl_xor(1)).
// Cross-validated on-device vs a pure-VALU fp32 path in round 4.
// ---------------------------------------------------------------------------
__global__ __launch_bounds__(64) void gemm_rope(
    const void* __restrict__ X, const float* __restrict__ W,
    float* __restrict__ Cf, __bf16* __restrict__ Cb,
    const int* __restrict__ tokpos, int aBf, int doRope)
{
    const int lane = threadIdx.x;
    const int quad = lane >> 4;
    const int l16  = lane & 15;
    const int m0 = blockIdx.x * 16;
    const int n0 = blockIdx.y * 64;

    const size_t aOff = (size_t)(m0 + l16) * D_MODEL + quad * 8;
    const float*  wrow = W + (size_t)(n0 + l16) * D_MODEL + quad * 8;

    floatx4 acc[4] = {};
    for (int k = 0; k < D_MODEL; k += 32) {
        const bf16x8 a = aBf ? *(const bf16x8*)((const __bf16*)X + aOff + k)
                             : load8f((const float*)X + aOff + k);
#pragma unroll
        for (int g = 0; g < 4; ++g) {
            const bf16x8 b = load8f(wrow + (size_t)g * 16 * D_MODEL + k);
            acc[g] = MFMA16(a, b, acc[g]);
        }
    }

#pragma unroll
    for (int g = 0; g < 4; ++g) {
        const int n = n0 + g * 16 + l16;
#pragma unroll
        for (int r = 0; r < 4; ++r) {
            const int t = m0 + quad * 4 + r;   // token row
            float v = acc[g][r];
            if (doRope) {
                const float vp = __shfl_xor(v, 1);   // pair partner column
                const int d  = n & (HEAD_DIM - 1);
                const int p2 = d & ~1;
                const float inv = exp2f(-(float)p2 * ROPE_C);
                const float ang = (float)tokpos[t & (SEQ - 1)] * inv;
                const float c = cosf(ang), s = sinf(ang);
                v = (d & 1) ? (vp * s + v * c) : (v * c - vp * s);
            }
            const size_t off = (size_t)t * D_MODEL + n;
            if (Cf) Cf[off] = v;
            else    Cb[off] = (__bf16)v;
        }
    }
}

// ---------------------------------------------------------------------------
// Causal flash attention (cross-validated in round 4). One wave per
// (b, h, 16-row q-tile). Q/K/V layout: [token][h*64+d]. 32 keys/iter:
// two 16x16 score tiles -> online softmax -> P via LDS (C->A layout, bf16)
// -> PV. O aliases Q (in-place): each block writes exactly the Q rectangle
// only it reads, and Q is register-resident before any store.
// ---------------------------------------------------------------------------
__global__ __launch_bounds__(64) void attn_fused(
    const __bf16* Q, const __bf16* __restrict__ K,
    const __bf16* __restrict__ V, __bf16* O)
{
    const int lane = threadIdx.x;
    const int quad = lane >> 4;
    const int l16  = lane & 15;
    const int q0 = blockIdx.x * 16;
    const int bh = blockIdx.y;
    const int b = bh >> 4, h = bh & (N_HEADS - 1);
    const size_t base = (size_t)b * SEQ * D_MODEL + (size_t)h * HEAD_DIM;

    const __bf16* qrow = Q + base + (size_t)(q0 + l16) * D_MODEL + quad * 8;
    const bf16x8 a0 = *(const bf16x8*)(qrow);
    const bf16x8 a1 = *(const bf16x8*)(qrow + 32);

    float m_i[4], l_i[4];
    floatx4 o_acc[4] = {};   // o_acc[g][r]: row q0+quad*4+r, dim g*16+l16
#pragma unroll
    for (int r = 0; r < 4; ++r) { m_i[r] = -__builtin_inff(); l_i[r] = 0.f; }

    __shared__ __bf16 P[16][32];

    for (int k0 = 0; k0 <= q0 + 15; k0 += 32) {
        const __bf16* krow = K + base + (size_t)(k0 + l16) * D_MODEL + quad * 8;
        const bf16x8 b00 = *(const bf16x8*)(krow);
        const bf16x8 b01 = *(const bf16x8*)(krow + 32);
        const bf16x8 b10 = *(const bf16x8*)(krow + 16 * D_MODEL);
        const bf16x8 b11 = *(const bf16x8*)(krow + 16 * D_MODEL + 32);
        floatx4 s0 = {}, s1 = {};
        s0 = MFMA16(a0, b00, s0); s0 = MFMA16(a1, b01, s0);
        s1 = MFMA16(a0, b10, s1); s1 = MFMA16(a1, b11, s1);

        float p0a[4], p1a[4];
#pragma unroll
        for (int r = 0; r < 4; ++r) {
            const int qg = q0 + quad * 4 + r;
            float v0 = (k0 + l16 > qg)      ? -__builtin_inff() : s0[r] * 0.125f;
            float v1 = (k0 + 16 + l16 > qg) ? -__builtin_inff() : s1[r] * 0.125f;
            float mx = fmaxf(v0, v1);
#pragma unroll
            for (int off = 1; off < 16; off <<= 1) mx = fmaxf(mx, __shfl_xor(mx, off));
            const float m_new = fmaxf(m_i[r], mx);
            const float alpha = __expf(m_i[r] - m_new);
            const float p0 = __expf(v0 - m_new);
            const float p1 = __expf(v1 - m_new);
            float rs = p0 + p1;
#pragma unroll
            for (int off = 1; off < 16; off <<= 1) rs += __shfl_xor(rs, off);
            l_i[r] = l_i[r] * alpha + rs;
            m_i[r] = m_new;
#pragma unroll
            for (int g = 0; g < 4; ++g) o_acc[g][r] *= alpha;
            p0a[r] = p0; p1a[r] = p1;
        }

        __syncthreads();
#pragma unroll
        for (int r = 0; r < 4; ++r) {
            P[quad * 4 + r][l16]      = (__bf16)p0a[r];
            P[quad * 4 + r][16 + l16] = (__bf16)p1a[r];
        }
        __syncthreads();
        const bf16x8 ap = *(const bf16x8*)(&P[l16][quad * 8]);

        const __bf16* vp = V + base + (size_t)(k0 + quad * 8) * D_MODEL + l16;
#pragma unroll
        for (int g = 0; g < 4; ++g) {
            bf16x8 vb;
#pragma unroll
            for (int j = 0; j < 8; ++j) vb[j] = vp[(size_t)j * D_MODEL + g * 16];
            o_acc[g] = MFMA16(ap, vb, o_acc[g]);
        }
    }

#pragma unroll
    for (int g = 0; g < 4; ++g)
#pragma unroll
        for (int r = 0; r < 4; ++r) {
            const int t = q0 + quad * 4 + r;
            O[base + (size_t)t * D_MODEL + g * 16 + l16] = (__bf16)(o_acc[g][r] / l_i[r]);
        }
}

// ---------------------------------------------------------------------------
// I/O: inputs fp32 (round-1 NaN forensics), output fp32 (reference output
// dtype; round 0/1/2-4 error pattern all consistent with fp32 readback).
// ws: Qb/Kb/Vb bf16, 24 MB total; attention output in-place over Qb.
// ---------------------------------------------------------------------------
extern "C" void kernel_launch(void* const* d_in, const int* in_sizes, int n_in,
                              void* d_out, int out_size, void* d_ws, size_t ws_size,
                              hipStream_t stream) {
    const float* x  = (const float*)d_in[0];
    const int* pos  = (const int*)d_in[1];
    const float* Wq = (const float*)d_in[2];
    const float* Wk = (const float*)d_in[3];
    const float* Wv = (const float*)d_in[4];
    const float* Wo = (const float*)d_in[5];
    float* out = (float*)d_out;

    const size_t xe = (size_t)M_TOK * D_MODEL;   // 4M elements
    __bf16* Qb = (__bf16*)d_ws;
    __bf16* Kb = Qb + xe;
    __bf16* Vb = Kb + xe;

    dim3 gGemm(M_TOK / 16, D_MODEL / 64);   // 256 x 16
    dim3 blk(64);

    // projections (+RoPE for Q,K): fp32 in, bf16 intermediate out
    gemm_rope<<<gGemm, blk, 0, stream>>>(x, Wq, nullptr, Qb, pos, 0, 1);
    gemm_rope<<<gGemm, blk, 0, stream>>>(x, Wk, nullptr, Kb, pos, 0, 1);
    gemm_rope<<<gGemm, blk, 0, stream>>>(x, Wv, nullptr, Vb, pos, 0, 0);

    // causal flash attention, in-place over Qb
    dim3 gAttn(SEQ / 16, 2 * N_HEADS);      // 128 x 32
    attn_fused<<<gAttn, blk, 0, stream>>>(Qb, Kb, Vb, Qb);

    // output projection: bf16 A (attn), fp32 W, *** float output ***
    gemm_rope<<<gGemm, blk, 0, stream>>>(Qb, Wo, out, nullptr, pos, 1, 0);
}